// Round 3
// baseline (391.943 us; speedup 1.0000x reference)
//
#include <hip/hip_runtime.h>
#include <math.h>

// ---------------------------------------------------------------------------
// GATv2 x2 + mean-pool + linear, MI355X.
// R2: aggregate uses 16-lanes-per-edge (float4/lane) -> 4-step swizzle reduce,
//     4 edges in flight + unroll-2 (8 edges/iter); single-kernel scan;
//     fill_csr fused with layer-1 dual GEMM; GROWS=32 GEMM w/ float4 staging.
// ---------------------------------------------------------------------------

#define NEG_BIG (-3.0e38f)

// ---------------- CSR build ----------------
// also zeroes zbuf[0..zn) (sums+cnts, consumed much later in-stream)
__global__ __launch_bounds__(256) void count_deg_kernel(
    const int* __restrict__ dst, int* __restrict__ deg, int E,
    float* __restrict__ zbuf, int zn) {
    int e = blockIdx.x * blockDim.x + threadIdx.x;
    if (e < zn) zbuf[e] = 0.f;
    if (e < E) atomicAdd(&deg[dst[e]], 1);
}

// single-block two-pass scan: deg[0..n) -> rowptr[0..n] (exclusive, rowptr[0]=0)
__global__ __launch_bounds__(1024) void scan_kernel(
    const int* __restrict__ deg, int* __restrict__ rowptr, int n) {
    __shared__ int tsum[1024];
    int t = threadIdx.x;
    int chunk = (n + 1023) >> 10;
    int s0 = t * chunk, s1 = min(n, s0 + chunk);
    int sum = 0;
    for (int i = s0; i < s1; ++i) sum += deg[i];
    tsum[t] = sum;
    __syncthreads();
    for (int off = 1; off < 1024; off <<= 1) {
        int x = (t >= off) ? tsum[t - off] : 0;
        __syncthreads();
        tsum[t] += x;
        __syncthreads();
    }
    int run = tsum[t] - sum;  // exclusive prefix of this chunk
    for (int i = s0; i < s1; ++i) { run += deg[i]; rowptr[i + 1] = run; }
    if (t == 0) rowptr[0] = 0;
}

// ---------------- dual GEMM body: xl = X*Wl + bl, xr = X*Wr + br ----------
#define GROWS 32
__device__ __forceinline__ void dual_gemm_body(
    int bid, int t,
    const float* __restrict__ X,
    const float* __restrict__ Wl, const float* __restrict__ bl,
    const float* __restrict__ Wr, const float* __restrict__ br,
    float* __restrict__ xl, float* __restrict__ xr, int n,
    float* WlS, float* WrS, float* xS) {
    // stage W (4096 floats each) via float4
    for (int i = t; i < 1024; i += 256) {
        ((float4*)WlS)[i] = ((const float4*)Wl)[i];
        ((float4*)WrS)[i] = ((const float4*)Wr)[i];
    }
    int row0 = bid * GROWS;
    // stage x tile (GROWS*64 = 2048 floats) via float4
    for (int i = t; i < GROWS * 16; i += 256) {
        int r = row0 + (i >> 4);
        float4 v = make_float4(0.f, 0.f, 0.f, 0.f);
        if (r < n) v = ((const float4*)(X + (size_t)r * 64))[i & 15];
        ((float4*)xS)[i] = v;
    }
    __syncthreads();
    int h  = t & 63;
    int rb = t >> 6;  // 0..3
    float accl[8], accr[8];
#pragma unroll
    for (int i = 0; i < 8; ++i) { accl[i] = 0.f; accr[i] = 0.f; }
    for (int d = 0; d < 64; ++d) {
        float wl = WlS[d * 64 + h];
        float wr = WrS[d * 64 + h];
#pragma unroll
        for (int i = 0; i < 8; ++i) {
            float xv = xS[(rb + 4 * i) * 64 + d];  // wave-uniform broadcast
            accl[i] += xv * wl;
            accr[i] += xv * wr;
        }
    }
    float blv = bl[h], brv = br[h];
#pragma unroll
    for (int i = 0; i < 8; ++i) {
        int r = row0 + rb + 4 * i;
        if (r < n) {
            xl[(size_t)r * 64 + h] = accl[i] + blv;
            xr[(size_t)r * 64 + h] = accr[i] + brv;
        }
    }
}

__global__ __launch_bounds__(256) void dual_gemm64_kernel(
    const float* __restrict__ X,
    const float* __restrict__ Wl, const float* __restrict__ bl,
    const float* __restrict__ Wr, const float* __restrict__ br,
    float* __restrict__ xl, float* __restrict__ xr, int n) {
    __shared__ float WlS[4096], WrS[4096], xS[GROWS * 64];
    dual_gemm_body(blockIdx.x, threadIdx.x, X, Wl, bl, Wr, br, xl, xr, n,
                   WlS, WrS, xS);
}

// fused: blocks [0,egrid) do CSR fill (countdown on deg), rest do gemm1
__global__ __launch_bounds__(256) void fill_gemm_kernel(
    const int* __restrict__ src, const int* __restrict__ dst,
    const int* __restrict__ rowptr, int* __restrict__ deg,
    int* __restrict__ csr_src, int E, int egrid,
    const float* __restrict__ X,
    const float* __restrict__ Wl, const float* __restrict__ bl,
    const float* __restrict__ Wr, const float* __restrict__ br,
    float* __restrict__ xl, float* __restrict__ xr, int n) {
    __shared__ float WlS[4096], WrS[4096], xS[GROWS * 64];
    if ((int)blockIdx.x < egrid) {
        int e = blockIdx.x * 256 + threadIdx.x;
        if (e < E) {
            int d = dst[e];
            int rem = atomicSub(&deg[d], 1);  // old value, 1..deg
            csr_src[rowptr[d] + rem - 1] = src[e];
        }
    } else {
        dual_gemm_body(blockIdx.x - egrid, threadIdx.x, X, Wl, bl, Wr, br,
                       xl, xr, n, WlS, WrS, xS);
    }
}

// ---------------- per-dst GATv2 aggregation ----------------
// wave = 4 groups x 16 lanes; group g handles edge p+g; lane l holds feats 4l..4l+3
__global__ __launch_bounds__(256) void gat_aggregate_kernel(
    const float* __restrict__ xl, const float* __restrict__ xr,
    const int* __restrict__ rowptr, const int* __restrict__ csr_src,
    const float* __restrict__ att, const float* __restrict__ bias,
    float* __restrict__ out, int n) {
    int wid  = (blockIdx.x * blockDim.x + threadIdx.x) >> 6;
    int lane = threadIdx.x & 63;
    if (wid >= n) return;
    int g = lane >> 4;   // edge slot within wave
    int l = lane & 15;   // feature quad
    int d = wid;

    float4 xr4  = ((const float4*)(xr + (size_t)d * 64))[l];
    float4 att4 = ((const float4*)att)[l];
    int beg = rowptr[d], end = rowptr[d + 1];

    float  m = NEG_BIG, s = 0.f;
    float4 acc = make_float4(0.f, 0.f, 0.f, 0.f);
    int p = beg;

    // main loop: 8 edges per iteration (2 per group), all active
    for (; p + 8 <= end; p += 8) {
        int i0 = csr_src[p + g];
        int i1 = csr_src[p + 4 + g];
        float4 x0 = ((const float4*)(xl + (size_t)i0 * 64))[l];
        float4 x1 = ((const float4*)(xl + (size_t)i1 * 64))[l];
        float z, c0, c1;
        c0 = 0.f; c1 = 0.f;
        z = x0.x + xr4.x; c0 += ((z > 0.f) ? z : 0.2f * z) * att4.x;
        z = x0.y + xr4.y; c0 += ((z > 0.f) ? z : 0.2f * z) * att4.y;
        z = x0.z + xr4.z; c0 += ((z > 0.f) ? z : 0.2f * z) * att4.z;
        z = x0.w + xr4.w; c0 += ((z > 0.f) ? z : 0.2f * z) * att4.w;
        z = x1.x + xr4.x; c1 += ((z > 0.f) ? z : 0.2f * z) * att4.x;
        z = x1.y + xr4.y; c1 += ((z > 0.f) ? z : 0.2f * z) * att4.y;
        z = x1.z + xr4.z; c1 += ((z > 0.f) ? z : 0.2f * z) * att4.z;
        z = x1.w + xr4.w; c1 += ((z > 0.f) ? z : 0.2f * z) * att4.w;
#pragma unroll
        for (int sh = 8; sh >= 1; sh >>= 1) {  // reduce within 16 lanes
            c0 += __shfl_xor(c0, sh);
            c1 += __shfl_xor(c1, sh);
        }
        float mn = fmaxf(m, fmaxf(c0, c1));
        float ra = __expf(m - mn);
        float p0 = __expf(c0 - mn);
        float p1 = __expf(c1 - mn);
        s = s * ra + p0 + p1;
        acc.x = acc.x * ra + p0 * x0.x + p1 * x1.x;
        acc.y = acc.y * ra + p0 * x0.y + p1 * x1.y;
        acc.z = acc.z * ra + p0 * x0.z + p1 * x1.z;
        acc.w = acc.w * ra + p0 * x0.w + p1 * x1.w;
        m = mn;
    }
    // tail: 4 edges per iteration, masked
    for (; p < end; p += 4) {
        int  e      = p + g;
        bool active = (e < end);
        int  i0     = active ? csr_src[e] : 0;
        float4 x0 = ((const float4*)(xl + (size_t)i0 * 64))[l];
        float z, c0 = 0.f;
        z = x0.x + xr4.x; c0 += ((z > 0.f) ? z : 0.2f * z) * att4.x;
        z = x0.y + xr4.y; c0 += ((z > 0.f) ? z : 0.2f * z) * att4.y;
        z = x0.z + xr4.z; c0 += ((z > 0.f) ? z : 0.2f * z) * att4.z;
        z = x0.w + xr4.w; c0 += ((z > 0.f) ? z : 0.2f * z) * att4.w;
#pragma unroll
        for (int sh = 8; sh >= 1; sh >>= 1) c0 += __shfl_xor(c0, sh);
        if (!active) c0 = -INFINITY;   // exp(-inf - finite) == 0, no NaN
        float mn = fmaxf(m, c0);       // mn >= m >= NEG_BIG stays finite
        float ra = __expf(m - mn);
        float cb = __expf(c0 - mn);
        s = s * ra + cb;
        acc.x = acc.x * ra + cb * x0.x;
        acc.y = acc.y * ra + cb * x0.y;
        acc.z = acc.z * ra + cb * x0.z;
        acc.w = acc.w * ra + cb * x0.w;
        m = mn;
    }
    // merge the 4 group accumulators (flash-style), xor 16 then xor 32
#pragma unroll
    for (int mask = 16; mask <= 32; mask <<= 1) {
        float mo = __shfl_xor(m, mask);
        float so = __shfl_xor(s, mask);
        float ax = __shfl_xor(acc.x, mask);
        float ay = __shfl_xor(acc.y, mask);
        float az = __shfl_xor(acc.z, mask);
        float aw = __shfl_xor(acc.w, mask);
        float mn = fmaxf(m, mo);
        float ra = __expf(m - mn);
        float rb = __expf(mo - mn);
        s = s * ra + so * rb;
        acc.x = acc.x * ra + ax * rb;
        acc.y = acc.y * ra + ay * rb;
        acc.z = acc.z * ra + az * rb;
        acc.w = acc.w * ra + aw * rb;
        m = mn;
    }
    if (g == 0) {
        float inv = (s > 0.f) ? (1.f / s) : 0.f;  // deg-0 -> 0 (+bias)
        float4 b4 = ((const float4*)bias)[l];
        float4 v;
        v.x = fmaxf(acc.x * inv + b4.x, 0.f);
        v.y = fmaxf(acc.y * inv + b4.y, 0.f);
        v.z = fmaxf(acc.z * inv + b4.z, 0.f);
        v.w = fmaxf(acc.w * inv + b4.w, 0.f);
        ((float4*)(out + (size_t)d * 64))[l] = v;
    }
}

// ---------------- mean pool over sorted batch ----------------
__global__ __launch_bounds__(256) void pool_kernel(
    const float* __restrict__ h, const int* __restrict__ batch,
    float* __restrict__ sums, float* __restrict__ cnts, int n, int nwaves) {
    int wid  = (blockIdx.x * blockDim.x + threadIdx.x) >> 6;
    int lane = threadIdx.x & 63;
    int per   = (n + nwaves - 1) / nwaves;
    int start = wid * per;
    int end   = min(n, start + per);
    if (start >= end) return;
    int cur   = batch[start];
    float acc = 0.f, cnt = 0.f;
    for (int i = start; i < end; ++i) {
        int g = batch[i];   // wave-uniform
        if (g != cur) {
            atomicAdd(&sums[cur * 64 + lane], acc);
            if (lane == 0) atomicAdd(&cnts[cur], cnt);
            acc = 0.f; cnt = 0.f; cur = g;
        }
        acc += h[(size_t)i * 64 + lane];
        cnt += 1.f;
    }
    atomicAdd(&sums[cur * 64 + lane], acc);
    if (lane == 0) atomicAdd(&cnts[cur], cnt);
}

// ---------------- final: out = (sums/cnt) @ lin_w + lin_b ----------------
__global__ __launch_bounds__(256) void final_kernel(
    const float* __restrict__ sums, const float* __restrict__ cnts,
    const float* __restrict__ lin_w, const float* __restrict__ lin_b,
    float* __restrict__ out, int total) {
    int tid = blockIdx.x * blockDim.x + threadIdx.x;
    if (tid >= total) return;
    int g = tid >> 5, o = tid & 31;
    float inv = 1.f / fmaxf(cnts[g], 1.f);
    float a = 0.f;
    for (int h = 0; h < 64; ++h) a += sums[g * 64 + h] * lin_w[h * 32 + o];
    out[tid] = a * inv + lin_b[o];
}

extern "C" void kernel_launch(void* const* d_in, const int* in_sizes, int n_in,
                              void* d_out, int out_size, void* d_ws, size_t ws_size,
                              hipStream_t stream) {
    const float* x     = (const float*)d_in[0];
    const int*   ei    = (const int*)d_in[1];
    const int*   batch = (const int*)d_in[2];
    const float* Wl1   = (const float*)d_in[3];
    const float* bl1   = (const float*)d_in[4];
    const float* Wr1   = (const float*)d_in[5];
    const float* br1   = (const float*)d_in[6];
    const float* att1  = (const float*)d_in[7];
    const float* bias1 = (const float*)d_in[8];
    const float* Wl2   = (const float*)d_in[9];
    const float* bl2   = (const float*)d_in[10];
    const float* Wr2   = (const float*)d_in[11];
    const float* br2   = (const float*)d_in[12];
    const float* att2  = (const float*)d_in[13];
    const float* bias2 = (const float*)d_in[14];
    const float* lin_w = (const float*)d_in[15];
    const float* lin_b = (const float*)d_in[16];
    float* out = (float*)d_out;

    const int N = in_sizes[0] / 64;
    const int E = in_sizes[1] / 2;
    const int G = out_size / 32;
    const int* src = ei;
    const int* dst = ei + E;

    // ---- workspace carve-up (256B-aligned) ----
    char*  ws  = (char*)d_ws;
    size_t off = 0;
    auto alloc = [&](size_t bytes) -> void* {
        void* p = ws + off;
        off += bytes;
        off = (off + 255) & ~(size_t)255;
        return p;
    };
    float* xl      = (float*)alloc((size_t)N * 64 * sizeof(float));
    float* xr      = (float*)alloc((size_t)N * 64 * sizeof(float));
    float* h1      = (float*)alloc((size_t)N * 64 * sizeof(float));
    float* h2      = (float*)alloc((size_t)N * 64 * sizeof(float));
    float* sums    = (float*)alloc((size_t)G * 64 * sizeof(float));  // contiguous
    float* cnts    = (float*)alloc((size_t)G * sizeof(float));       //  with sums
    int*   deg     = (int*)alloc((size_t)N * sizeof(int));
    int*   rowptr  = (int*)alloc((size_t)(N + 1) * sizeof(int));
    int*   csr_src = (int*)alloc((size_t)E * sizeof(int));

    hipMemsetAsync(deg, 0, (size_t)N * sizeof(int), stream);

    int egrid = (E + 255) / 256;
    int ggrid = (N + GROWS - 1) / GROWS;
    int agrid = (N + 3) / 4;  // 4 waves/block, 1 wave per dst node

    // ---- CSR count + scan ----
    count_deg_kernel<<<egrid, 256, 0, stream>>>(dst, deg, E, sums, G * 65);
    scan_kernel<<<1, 1024, 0, stream>>>(deg, rowptr, N);

    // ---- CSR fill fused with layer-1 dual GEMM (independent work) ----
    fill_gemm_kernel<<<egrid + ggrid, 256, 0, stream>>>(
        src, dst, rowptr, deg, csr_src, E, egrid,
        x, Wl1, bl1, Wr1, br1, xl, xr, N);

    gat_aggregate_kernel<<<agrid, 256, 0, stream>>>(xl, xr, rowptr, csr_src, att1, bias1, h1, N);

    // ---- layer 2 ----
    dual_gemm64_kernel<<<ggrid, 256, 0, stream>>>(h1, Wl2, bl2, Wr2, br2, xl, xr, N);
    gat_aggregate_kernel<<<agrid, 256, 0, stream>>>(xl, xr, rowptr, csr_src, att2, bias2, h2, N);

    // ---- pool + final linear ----
    const int NWAVES = 1024;
    pool_kernel<<<256, 256, 0, stream>>>(h2, batch, sums, cnts, N, NWAVES);
    int total = G * 32;
    final_kernel<<<(total + 255) / 256, 256, 0, stream>>>(sums, cnts, lin_w, lin_b, out, total);
}

// Round 4
// 308.883 us; speedup vs baseline: 1.2689x; 1.2689x over previous
//
#include <hip/hip_runtime.h>
#include <math.h>

// ---------------------------------------------------------------------------
// GATv2 x2 + mean-pool + linear, MI355X.
// R3: revert single-block scan (78us on 1 CU!) to 3-phase parallel scan.
//     Keep R2's 16-lane-per-edge aggregate + fused fill/gemm1.
// ---------------------------------------------------------------------------

#define NEG_BIG (-3.0e38f)

// ---------------- CSR build ----------------
// also zeroes zbuf[0..zn) (sums+cnts, consumed much later in-stream)
__global__ __launch_bounds__(256) void count_deg_kernel(
    const int* __restrict__ dst, int* __restrict__ deg, int E,
    float* __restrict__ zbuf, int zn) {
    int e = blockIdx.x * blockDim.x + threadIdx.x;
    if (e < zn) zbuf[e] = 0.f;
    if (e < E) atomicAdd(&deg[dst[e]], 1);
}

#define SCAN_B 256
// phase 1: per-block sums of deg
__global__ __launch_bounds__(SCAN_B) void block_sum_kernel(
    const int* __restrict__ deg, int* __restrict__ bsum, int n) {
    __shared__ int wsum[4];
    int i = blockIdx.x * SCAN_B + threadIdx.x;
    int v = (i < n) ? deg[i] : 0;
    v += __shfl_down(v, 32);
    v += __shfl_down(v, 16);
    v += __shfl_down(v, 8);
    v += __shfl_down(v, 4);
    v += __shfl_down(v, 2);
    v += __shfl_down(v, 1);
    if ((threadIdx.x & 63) == 0) wsum[threadIdx.x >> 6] = v;
    __syncthreads();
    if (threadIdx.x == 0) bsum[blockIdx.x] = wsum[0] + wsum[1] + wsum[2] + wsum[3];
}

// phase 2: exclusive scan of block sums (nb <= 1024), single block
__global__ __launch_bounds__(1024) void scan_bsum_kernel(int* bsum, int nb) {
    __shared__ int buf[1024];
    int t = threadIdx.x;
    int v = (t < nb) ? bsum[t] : 0;
    buf[t] = v;
    __syncthreads();
    for (int off = 1; off < 1024; off <<= 1) {
        int x = (t >= off) ? buf[t - off] : 0;
        __syncthreads();
        buf[t] += x;
        __syncthreads();
    }
    if (t < nb) bsum[t] = buf[t] - v;  // exclusive
}

// phase 3: re-scan each block, add offset, write rowptr
__global__ __launch_bounds__(SCAN_B) void scan_write_kernel(
    const int* __restrict__ deg, const int* __restrict__ bsum,
    int* __restrict__ rowptr, int n) {
    __shared__ int buf[SCAN_B];
    int i = blockIdx.x * SCAN_B + threadIdx.x;
    int t = threadIdx.x;
    int v = (i < n) ? deg[i] : 0;
    buf[t] = v;
    __syncthreads();
    for (int off = 1; off < SCAN_B; off <<= 1) {
        int x = (t >= off) ? buf[t - off] : 0;
        __syncthreads();
        buf[t] += x;
        __syncthreads();
    }
    if (i < n) rowptr[i + 1] = buf[t] + bsum[blockIdx.x];  // inclusive + offset
    if (i == 0) rowptr[0] = 0;
}

// ---------------- dual GEMM body: xl = X*Wl + bl, xr = X*Wr + br ----------
#define GROWS 32
__device__ __forceinline__ void dual_gemm_body(
    int bid, int t,
    const float* __restrict__ X,
    const float* __restrict__ Wl, const float* __restrict__ bl,
    const float* __restrict__ Wr, const float* __restrict__ br,
    float* __restrict__ xl, float* __restrict__ xr, int n,
    float* WlS, float* WrS, float* xS) {
    // stage W (4096 floats each) via float4
    for (int i = t; i < 1024; i += 256) {
        ((float4*)WlS)[i] = ((const float4*)Wl)[i];
        ((float4*)WrS)[i] = ((const float4*)Wr)[i];
    }
    int row0 = bid * GROWS;
    // stage x tile (GROWS*64 = 2048 floats) via float4
    for (int i = t; i < GROWS * 16; i += 256) {
        int r = row0 + (i >> 4);
        float4 v = make_float4(0.f, 0.f, 0.f, 0.f);
        if (r < n) v = ((const float4*)(X + (size_t)r * 64))[i & 15];
        ((float4*)xS)[i] = v;
    }
    __syncthreads();
    int h  = t & 63;
    int rb = t >> 6;  // 0..3
    float accl[8], accr[8];
#pragma unroll
    for (int i = 0; i < 8; ++i) { accl[i] = 0.f; accr[i] = 0.f; }
    for (int d = 0; d < 64; ++d) {
        float wl = WlS[d * 64 + h];
        float wr = WrS[d * 64 + h];
#pragma unroll
        for (int i = 0; i < 8; ++i) {
            float xv = xS[(rb + 4 * i) * 64 + d];  // wave-uniform broadcast
            accl[i] += xv * wl;
            accr[i] += xv * wr;
        }
    }
    float blv = bl[h], brv = br[h];
#pragma unroll
    for (int i = 0; i < 8; ++i) {
        int r = row0 + rb + 4 * i;
        if (r < n) {
            xl[(size_t)r * 64 + h] = accl[i] + blv;
            xr[(size_t)r * 64 + h] = accr[i] + brv;
        }
    }
}

__global__ __launch_bounds__(256) void dual_gemm64_kernel(
    const float* __restrict__ X,
    const float* __restrict__ Wl, const float* __restrict__ bl,
    const float* __restrict__ Wr, const float* __restrict__ br,
    float* __restrict__ xl, float* __restrict__ xr, int n) {
    __shared__ float WlS[4096], WrS[4096], xS[GROWS * 64];
    dual_gemm_body(blockIdx.x, threadIdx.x, X, Wl, bl, Wr, br, xl, xr, n,
                   WlS, WrS, xS);
}

// fused: blocks [0,egrid) do CSR fill (countdown on deg), rest do gemm1
__global__ __launch_bounds__(256) void fill_gemm_kernel(
    const int* __restrict__ src, const int* __restrict__ dst,
    const int* __restrict__ rowptr, int* __restrict__ deg,
    int* __restrict__ csr_src, int E, int egrid,
    const float* __restrict__ X,
    const float* __restrict__ Wl, const float* __restrict__ bl,
    const float* __restrict__ Wr, const float* __restrict__ br,
    float* __restrict__ xl, float* __restrict__ xr, int n) {
    __shared__ float WlS[4096], WrS[4096], xS[GROWS * 64];
    if ((int)blockIdx.x < egrid) {
        int e = blockIdx.x * 256 + threadIdx.x;
        if (e < E) {
            int d = dst[e];
            int rem = atomicSub(&deg[d], 1);  // old value, 1..deg
            csr_src[rowptr[d] + rem - 1] = src[e];
        }
    } else {
        dual_gemm_body(blockIdx.x - egrid, threadIdx.x, X, Wl, bl, Wr, br,
                       xl, xr, n, WlS, WrS, xS);
    }
}

// ---------------- per-dst GATv2 aggregation ----------------
// wave = 4 groups x 16 lanes; group g handles edge p+g; lane l holds feats 4l..4l+3
__global__ __launch_bounds__(256) void gat_aggregate_kernel(
    const float* __restrict__ xl, const float* __restrict__ xr,
    const int* __restrict__ rowptr, const int* __restrict__ csr_src,
    const float* __restrict__ att, const float* __restrict__ bias,
    float* __restrict__ out, int n) {
    int wid  = (blockIdx.x * blockDim.x + threadIdx.x) >> 6;
    int lane = threadIdx.x & 63;
    if (wid >= n) return;
    int g = lane >> 4;   // edge slot within wave
    int l = lane & 15;   // feature quad
    int d = wid;

    float4 xr4  = ((const float4*)(xr + (size_t)d * 64))[l];
    float4 att4 = ((const float4*)att)[l];
    int beg = rowptr[d], end = rowptr[d + 1];

    float  m = NEG_BIG, s = 0.f;
    float4 acc = make_float4(0.f, 0.f, 0.f, 0.f);
    int p = beg;

    // main loop: 8 edges per iteration (2 per group), all active
    for (; p + 8 <= end; p += 8) {
        int i0 = csr_src[p + g];
        int i1 = csr_src[p + 4 + g];
        float4 x0 = ((const float4*)(xl + (size_t)i0 * 64))[l];
        float4 x1 = ((const float4*)(xl + (size_t)i1 * 64))[l];
        float z, c0, c1;
        c0 = 0.f; c1 = 0.f;
        z = x0.x + xr4.x; c0 += ((z > 0.f) ? z : 0.2f * z) * att4.x;
        z = x0.y + xr4.y; c0 += ((z > 0.f) ? z : 0.2f * z) * att4.y;
        z = x0.z + xr4.z; c0 += ((z > 0.f) ? z : 0.2f * z) * att4.z;
        z = x0.w + xr4.w; c0 += ((z > 0.f) ? z : 0.2f * z) * att4.w;
        z = x1.x + xr4.x; c1 += ((z > 0.f) ? z : 0.2f * z) * att4.x;
        z = x1.y + xr4.y; c1 += ((z > 0.f) ? z : 0.2f * z) * att4.y;
        z = x1.z + xr4.z; c1 += ((z > 0.f) ? z : 0.2f * z) * att4.z;
        z = x1.w + xr4.w; c1 += ((z > 0.f) ? z : 0.2f * z) * att4.w;
#pragma unroll
        for (int sh = 8; sh >= 1; sh >>= 1) {  // reduce within 16 lanes
            c0 += __shfl_xor(c0, sh);
            c1 += __shfl_xor(c1, sh);
        }
        float mn = fmaxf(m, fmaxf(c0, c1));
        float ra = __expf(m - mn);
        float p0 = __expf(c0 - mn);
        float p1 = __expf(c1 - mn);
        s = s * ra + p0 + p1;
        acc.x = acc.x * ra + p0 * x0.x + p1 * x1.x;
        acc.y = acc.y * ra + p0 * x0.y + p1 * x1.y;
        acc.z = acc.z * ra + p0 * x0.z + p1 * x1.z;
        acc.w = acc.w * ra + p0 * x0.w + p1 * x1.w;
        m = mn;
    }
    // tail: 4 edges per iteration, masked
    for (; p < end; p += 4) {
        int  e      = p + g;
        bool active = (e < end);
        int  i0     = active ? csr_src[e] : 0;
        float4 x0 = ((const float4*)(xl + (size_t)i0 * 64))[l];
        float z, c0 = 0.f;
        z = x0.x + xr4.x; c0 += ((z > 0.f) ? z : 0.2f * z) * att4.x;
        z = x0.y + xr4.y; c0 += ((z > 0.f) ? z : 0.2f * z) * att4.y;
        z = x0.z + xr4.z; c0 += ((z > 0.f) ? z : 0.2f * z) * att4.z;
        z = x0.w + xr4.w; c0 += ((z > 0.f) ? z : 0.2f * z) * att4.w;
#pragma unroll
        for (int sh = 8; sh >= 1; sh >>= 1) c0 += __shfl_xor(c0, sh);
        if (!active) c0 = -INFINITY;   // exp(-inf - finite) == 0, no NaN
        float mn = fmaxf(m, c0);       // mn >= m >= NEG_BIG stays finite
        float ra = __expf(m - mn);
        float cb = __expf(c0 - mn);
        s = s * ra + cb;
        acc.x = acc.x * ra + cb * x0.x;
        acc.y = acc.y * ra + cb * x0.y;
        acc.z = acc.z * ra + cb * x0.z;
        acc.w = acc.w * ra + cb * x0.w;
        m = mn;
    }
    // merge the 4 group accumulators (flash-style), xor 16 then xor 32
#pragma unroll
    for (int mask = 16; mask <= 32; mask <<= 1) {
        float mo = __shfl_xor(m, mask);
        float so = __shfl_xor(s, mask);
        float ax = __shfl_xor(acc.x, mask);
        float ay = __shfl_xor(acc.y, mask);
        float az = __shfl_xor(acc.z, mask);
        float aw = __shfl_xor(acc.w, mask);
        float mn = fmaxf(m, mo);
        float ra = __expf(m - mn);
        float rb = __expf(mo - mn);
        s = s * ra + so * rb;
        acc.x = acc.x * ra + ax * rb;
        acc.y = acc.y * ra + ay * rb;
        acc.z = acc.z * ra + az * rb;
        acc.w = acc.w * ra + aw * rb;
        m = mn;
    }
    if (g == 0) {
        float inv = (s > 0.f) ? (1.f / s) : 0.f;  // deg-0 -> 0 (+bias)
        float4 b4 = ((const float4*)bias)[l];
        float4 v;
        v.x = fmaxf(acc.x * inv + b4.x, 0.f);
        v.y = fmaxf(acc.y * inv + b4.y, 0.f);
        v.z = fmaxf(acc.z * inv + b4.z, 0.f);
        v.w = fmaxf(acc.w * inv + b4.w, 0.f);
        ((float4*)(out + (size_t)d * 64))[l] = v;
    }
}

// ---------------- mean pool over sorted batch ----------------
__global__ __launch_bounds__(256) void pool_kernel(
    const float* __restrict__ h, const int* __restrict__ batch,
    float* __restrict__ sums, float* __restrict__ cnts, int n, int nwaves) {
    int wid  = (blockIdx.x * blockDim.x + threadIdx.x) >> 6;
    int lane = threadIdx.x & 63;
    int per   = (n + nwaves - 1) / nwaves;
    int start = wid * per;
    int end   = min(n, start + per);
    if (start >= end) return;
    int cur   = batch[start];
    float acc = 0.f, cnt = 0.f;
    for (int i = start; i < end; ++i) {
        int g = batch[i];   // wave-uniform
        if (g != cur) {
            atomicAdd(&sums[cur * 64 + lane], acc);
            if (lane == 0) atomicAdd(&cnts[cur], cnt);
            acc = 0.f; cnt = 0.f; cur = g;
        }
        acc += h[(size_t)i * 64 + lane];
        cnt += 1.f;
    }
    atomicAdd(&sums[cur * 64 + lane], acc);
    if (lane == 0) atomicAdd(&cnts[cur], cnt);
}

// ---------------- final: out = (sums/cnt) @ lin_w + lin_b ----------------
__global__ __launch_bounds__(256) void final_kernel(
    const float* __restrict__ sums, const float* __restrict__ cnts,
    const float* __restrict__ lin_w, const float* __restrict__ lin_b,
    float* __restrict__ out, int total) {
    int tid = blockIdx.x * blockDim.x + threadIdx.x;
    if (tid >= total) return;
    int g = tid >> 5, o = tid & 31;
    float inv = 1.f / fmaxf(cnts[g], 1.f);
    float a = 0.f;
    for (int h = 0; h < 64; ++h) a += sums[g * 64 + h] * lin_w[h * 32 + o];
    out[tid] = a * inv + lin_b[o];
}

extern "C" void kernel_launch(void* const* d_in, const int* in_sizes, int n_in,
                              void* d_out, int out_size, void* d_ws, size_t ws_size,
                              hipStream_t stream) {
    const float* x     = (const float*)d_in[0];
    const int*   ei    = (const int*)d_in[1];
    const int*   batch = (const int*)d_in[2];
    const float* Wl1   = (const float*)d_in[3];
    const float* bl1   = (const float*)d_in[4];
    const float* Wr1   = (const float*)d_in[5];
    const float* br1   = (const float*)d_in[6];
    const float* att1  = (const float*)d_in[7];
    const float* bias1 = (const float*)d_in[8];
    const float* Wl2   = (const float*)d_in[9];
    const float* bl2   = (const float*)d_in[10];
    const float* Wr2   = (const float*)d_in[11];
    const float* br2   = (const float*)d_in[12];
    const float* att2  = (const float*)d_in[13];
    const float* bias2 = (const float*)d_in[14];
    const float* lin_w = (const float*)d_in[15];
    const float* lin_b = (const float*)d_in[16];
    float* out = (float*)d_out;

    const int N = in_sizes[0] / 64;
    const int E = in_sizes[1] / 2;
    const int G = out_size / 32;
    const int* src = ei;
    const int* dst = ei + E;

    // ---- workspace carve-up (256B-aligned) ----
    char*  ws  = (char*)d_ws;
    size_t off = 0;
    auto alloc = [&](size_t bytes) -> void* {
        void* p = ws + off;
        off += bytes;
        off = (off + 255) & ~(size_t)255;
        return p;
    };
    float* xl      = (float*)alloc((size_t)N * 64 * sizeof(float));
    float* xr      = (float*)alloc((size_t)N * 64 * sizeof(float));
    float* h1      = (float*)alloc((size_t)N * 64 * sizeof(float));
    float* h2      = (float*)alloc((size_t)N * 64 * sizeof(float));
    float* sums    = (float*)alloc((size_t)G * 64 * sizeof(float));  // contiguous
    float* cnts    = (float*)alloc((size_t)G * sizeof(float));       //  with sums
    int*   deg     = (int*)alloc((size_t)N * sizeof(int));
    int*   rowptr  = (int*)alloc((size_t)(N + 1) * sizeof(int));
    int*   bsum    = (int*)alloc((size_t)1024 * sizeof(int));
    int*   csr_src = (int*)alloc((size_t)E * sizeof(int));

    hipMemsetAsync(deg, 0, (size_t)N * sizeof(int), stream);

    int egrid = (E + 255) / 256;
    int ggrid = (N + GROWS - 1) / GROWS;
    int agrid = (N + 3) / 4;  // 4 waves/block, 1 wave per dst node
    int nb    = (N + SCAN_B - 1) / SCAN_B;  // 196 for N=50000 (<=1024 req'd)

    // ---- CSR count + 3-phase parallel scan ----
    count_deg_kernel<<<egrid, 256, 0, stream>>>(dst, deg, E, sums, G * 65);
    block_sum_kernel<<<nb, SCAN_B, 0, stream>>>(deg, bsum, N);
    scan_bsum_kernel<<<1, 1024, 0, stream>>>(bsum, nb);
    scan_write_kernel<<<nb, SCAN_B, 0, stream>>>(deg, bsum, rowptr, N);

    // ---- CSR fill fused with layer-1 dual GEMM (independent work) ----
    fill_gemm_kernel<<<egrid + ggrid, 256, 0, stream>>>(
        src, dst, rowptr, deg, csr_src, E, egrid,
        x, Wl1, bl1, Wr1, br1, xl, xr, N);

    gat_aggregate_kernel<<<agrid, 256, 0, stream>>>(xl, xr, rowptr, csr_src, att1, bias1, h1, N);

    // ---- layer 2 ----
    dual_gemm64_kernel<<<ggrid, 256, 0, stream>>>(h1, Wl2, bl2, Wr2, br2, xl, xr, N);
    gat_aggregate_kernel<<<agrid, 256, 0, stream>>>(xl, xr, rowptr, csr_src, att2, bias2, h2, N);

    // ---- pool + final linear ----
    const int NWAVES = 1024;
    pool_kernel<<<256, 256, 0, stream>>>(h2, batch, sums, cnts, N, NWAVES);
    int total = G * 32;
    final_kernel<<<(total + 255) / 256, 256, 0, stream>>>(sums, cnts, lin_w, lin_b, out, total);
}

// Round 5
// 289.219 us; speedup vs baseline: 1.3552x; 1.0680x over previous
//
#include <hip/hip_runtime.h>
#include <math.h>

// ---------------------------------------------------------------------------
// GATv2 x2 + mean-pool + linear, MI355X.
// R4: CSR (count+scan+fill: 2 passes, 2 atomics/edge, ~130us) replaced by
//     one-pass ELL fill (1 atomic + 1 nontemporal store per edge) with
//     capacity-48 rows + overflow list (Poisson(16) tail, empty in practice).
//     h2 aliased onto h1; single fused memset; 12 -> 8 dispatches.
// ---------------------------------------------------------------------------

#define NEG_BIG (-3.0e38f)
#define ELLC    48
#define OVF_CAP 65536

// ---------------- ELL fill: one pass over edges ----------------
__global__ __launch_bounds__(256) void ell_fill_kernel(
    const int* __restrict__ src, const int* __restrict__ dst,
    int* __restrict__ cnt, int* __restrict__ ell,
    int* __restrict__ novf, int* __restrict__ ovf_dst, int* __restrict__ ovf_src,
    int E) {
    int e = blockIdx.x * 256 + threadIdx.x;
    if (e >= E) return;
    int d = dst[e];
    int s = src[e];
    int pos = atomicAdd(&cnt[d], 1);
    if (pos < ELLC) {
        // nontemporal: no-allocate, avoids L2 RFO line ping-pong on the
        // random 4B scatter (R4's 16x write amplification)
        __builtin_nontemporal_store(s, &ell[d * ELLC + pos]);
    } else {  // practically never (P(deg>48) ~ 5e-11 per node)
        int j = atomicAdd(novf, 1);
        if (j < OVF_CAP) { ovf_dst[j] = d; ovf_src[j] = s; }
    }
}

// ---------------- dual GEMM: xl = X*Wl + bl, xr = X*Wr + br ----------------
#define GROWS 32
__global__ __launch_bounds__(256) void dual_gemm64_kernel(
    const float* __restrict__ X,
    const float* __restrict__ Wl, const float* __restrict__ bl,
    const float* __restrict__ Wr, const float* __restrict__ br,
    float* __restrict__ xl, float* __restrict__ xr, int n) {
    __shared__ float WlS[4096], WrS[4096], xS[GROWS * 64];
    int t = threadIdx.x;
    for (int i = t; i < 1024; i += 256) {
        ((float4*)WlS)[i] = ((const float4*)Wl)[i];
        ((float4*)WrS)[i] = ((const float4*)Wr)[i];
    }
    int row0 = blockIdx.x * GROWS;
    for (int i = t; i < GROWS * 16; i += 256) {
        int r = row0 + (i >> 4);
        float4 v = make_float4(0.f, 0.f, 0.f, 0.f);
        if (r < n) v = ((const float4*)(X + (size_t)r * 64))[i & 15];
        ((float4*)xS)[i] = v;
    }
    __syncthreads();
    int h  = t & 63;
    int rb = t >> 6;  // 0..3
    float accl[8], accr[8];
#pragma unroll
    for (int i = 0; i < 8; ++i) { accl[i] = 0.f; accr[i] = 0.f; }
    for (int d = 0; d < 64; ++d) {
        float wl = WlS[d * 64 + h];
        float wr = WrS[d * 64 + h];
#pragma unroll
        for (int i = 0; i < 8; ++i) {
            float xv = xS[(rb + 4 * i) * 64 + d];  // wave-uniform broadcast
            accl[i] += xv * wl;
            accr[i] += xv * wr;
        }
    }
    float blv = bl[h], brv = br[h];
#pragma unroll
    for (int i = 0; i < 8; ++i) {
        int r = row0 + rb + 4 * i;
        if (r < n) {
            xl[(size_t)r * 64 + h] = accl[i] + blv;
            xr[(size_t)r * 64 + h] = accr[i] + brv;
        }
    }
}

// ---------------- per-dst GATv2 aggregation (ELL) ----------------
// wave = 4 groups x 16 lanes; group g handles edge p+g; lane l holds feats 4l..4l+3
__global__ __launch_bounds__(256) void gat_aggregate_kernel(
    const float* __restrict__ xl, const float* __restrict__ xr,
    const int* __restrict__ cnt, const int* __restrict__ ell,
    const int* __restrict__ novf, const int* __restrict__ ovf_dst,
    const int* __restrict__ ovf_src,
    const float* __restrict__ att, const float* __restrict__ bias,
    float* __restrict__ out, int n) {
    int wid  = (blockIdx.x * blockDim.x + threadIdx.x) >> 6;
    int lane = threadIdx.x & 63;
    if (wid >= n) return;
    int g = lane >> 4;   // edge slot within wave
    int l = lane & 15;   // feature quad
    int d = wid;

    float4 xr4  = ((const float4*)(xr + (size_t)d * 64))[l];
    float4 att4 = ((const float4*)att)[l];
    int deg_d = cnt[d];
    int beg = d * ELLC;
    int end = beg + min(deg_d, ELLC);

    float  m = NEG_BIG, s = 0.f;
    float4 acc = make_float4(0.f, 0.f, 0.f, 0.f);
    int p = beg;

    // main loop: 8 edges per iteration (2 per group), all active
    for (; p + 8 <= end; p += 8) {
        int i0 = ell[p + g];
        int i1 = ell[p + 4 + g];
        float4 x0 = ((const float4*)(xl + (size_t)i0 * 64))[l];
        float4 x1 = ((const float4*)(xl + (size_t)i1 * 64))[l];
        float z, c0 = 0.f, c1 = 0.f;
        z = x0.x + xr4.x; c0 += ((z > 0.f) ? z : 0.2f * z) * att4.x;
        z = x0.y + xr4.y; c0 += ((z > 0.f) ? z : 0.2f * z) * att4.y;
        z = x0.z + xr4.z; c0 += ((z > 0.f) ? z : 0.2f * z) * att4.z;
        z = x0.w + xr4.w; c0 += ((z > 0.f) ? z : 0.2f * z) * att4.w;
        z = x1.x + xr4.x; c1 += ((z > 0.f) ? z : 0.2f * z) * att4.x;
        z = x1.y + xr4.y; c1 += ((z > 0.f) ? z : 0.2f * z) * att4.y;
        z = x1.z + xr4.z; c1 += ((z > 0.f) ? z : 0.2f * z) * att4.z;
        z = x1.w + xr4.w; c1 += ((z > 0.f) ? z : 0.2f * z) * att4.w;
#pragma unroll
        for (int sh = 8; sh >= 1; sh >>= 1) {  // reduce within 16 lanes
            c0 += __shfl_xor(c0, sh);
            c1 += __shfl_xor(c1, sh);
        }
        float mn = fmaxf(m, fmaxf(c0, c1));
        float ra = __expf(m - mn);
        float p0 = __expf(c0 - mn);
        float p1 = __expf(c1 - mn);
        s = s * ra + p0 + p1;
        acc.x = acc.x * ra + p0 * x0.x + p1 * x1.x;
        acc.y = acc.y * ra + p0 * x0.y + p1 * x1.y;
        acc.z = acc.z * ra + p0 * x0.z + p1 * x1.z;
        acc.w = acc.w * ra + p0 * x0.w + p1 * x1.w;
        m = mn;
    }
    // tail: 4 edges per iteration, masked
    for (; p < end; p += 4) {
        int  e      = p + g;
        bool active = (e < end);
        int  i0     = active ? ell[e] : 0;
        float4 x0 = ((const float4*)(xl + (size_t)i0 * 64))[l];
        float z, c0 = 0.f;
        z = x0.x + xr4.x; c0 += ((z > 0.f) ? z : 0.2f * z) * att4.x;
        z = x0.y + xr4.y; c0 += ((z > 0.f) ? z : 0.2f * z) * att4.y;
        z = x0.z + xr4.z; c0 += ((z > 0.f) ? z : 0.2f * z) * att4.z;
        z = x0.w + xr4.w; c0 += ((z > 0.f) ? z : 0.2f * z) * att4.w;
#pragma unroll
        for (int sh = 8; sh >= 1; sh >>= 1) c0 += __shfl_xor(c0, sh);
        if (!active) c0 = -INFINITY;   // exp(-inf - finite) == 0, no NaN
        float mn = fmaxf(m, c0);       // mn >= m >= NEG_BIG stays finite
        float ra = __expf(m - mn);
        float cb = __expf(c0 - mn);
        s = s * ra + cb;
        acc.x = acc.x * ra + cb * x0.x;
        acc.y = acc.y * ra + cb * x0.y;
        acc.z = acc.z * ra + cb * x0.z;
        acc.w = acc.w * ra + cb * x0.w;
        m = mn;
    }
    // overflow fold (deg > ELLC): scan tiny global list; empty in practice
    if (deg_d > ELLC) {
        int no = min(*novf, OVF_CAP);
        for (int j = g; j < no; j += 4) {
            bool active = (ovf_dst[j] == d);
            int  i0     = active ? ovf_src[j] : 0;
            float4 x0 = ((const float4*)(xl + (size_t)i0 * 64))[l];
            float z, c0 = 0.f;
            z = x0.x + xr4.x; c0 += ((z > 0.f) ? z : 0.2f * z) * att4.x;
            z = x0.y + xr4.y; c0 += ((z > 0.f) ? z : 0.2f * z) * att4.y;
            z = x0.z + xr4.z; c0 += ((z > 0.f) ? z : 0.2f * z) * att4.z;
            z = x0.w + xr4.w; c0 += ((z > 0.f) ? z : 0.2f * z) * att4.w;
#pragma unroll
            for (int sh = 8; sh >= 1; sh >>= 1) c0 += __shfl_xor(c0, sh);
            if (!active) c0 = -INFINITY;
            float mn = fmaxf(m, c0);
            float ra = __expf(m - mn);
            float cb = __expf(c0 - mn);
            s = s * ra + cb;
            acc.x = acc.x * ra + cb * x0.x;
            acc.y = acc.y * ra + cb * x0.y;
            acc.z = acc.z * ra + cb * x0.z;
            acc.w = acc.w * ra + cb * x0.w;
            m = mn;
        }
    }
    // merge the 4 group accumulators (flash-style), xor 16 then xor 32
#pragma unroll
    for (int mask = 16; mask <= 32; mask <<= 1) {
        float mo = __shfl_xor(m, mask);
        float so = __shfl_xor(s, mask);
        float ax = __shfl_xor(acc.x, mask);
        float ay = __shfl_xor(acc.y, mask);
        float az = __shfl_xor(acc.z, mask);
        float aw = __shfl_xor(acc.w, mask);
        float mn = fmaxf(m, mo);
        float ra = __expf(m - mn);
        float rb = __expf(mo - mn);
        s = s * ra + so * rb;
        acc.x = acc.x * ra + ax * rb;
        acc.y = acc.y * ra + ay * rb;
        acc.z = acc.z * ra + az * rb;
        acc.w = acc.w * ra + aw * rb;
        m = mn;
    }
    if (g == 0) {
        float inv = (s > 0.f) ? (1.f / s) : 0.f;  // deg-0 -> 0 (+bias)
        float4 b4 = ((const float4*)bias)[l];
        float4 v;
        v.x = fmaxf(acc.x * inv + b4.x, 0.f);
        v.y = fmaxf(acc.y * inv + b4.y, 0.f);
        v.z = fmaxf(acc.z * inv + b4.z, 0.f);
        v.w = fmaxf(acc.w * inv + b4.w, 0.f);
        ((float4*)(out + (size_t)d * 64))[l] = v;
    }
}

// ---------------- mean pool over sorted batch ----------------
__global__ __launch_bounds__(256) void pool_kernel(
    const float* __restrict__ h, const int* __restrict__ batch,
    float* __restrict__ sums, float* __restrict__ cnts, int n, int nwaves) {
    int wid  = (blockIdx.x * blockDim.x + threadIdx.x) >> 6;
    int lane = threadIdx.x & 63;
    int per   = (n + nwaves - 1) / nwaves;
    int start = wid * per;
    int end   = min(n, start + per);
    if (start >= end) return;
    int cur   = batch[start];
    float acc = 0.f, cnt = 0.f;
    for (int i = start; i < end; ++i) {
        int g = batch[i];   // wave-uniform
        if (g != cur) {
            atomicAdd(&sums[cur * 64 + lane], acc);
            if (lane == 0) atomicAdd(&cnts[cur], cnt);
            acc = 0.f; cnt = 0.f; cur = g;
        }
        acc += h[(size_t)i * 64 + lane];
        cnt += 1.f;
    }
    atomicAdd(&sums[cur * 64 + lane], acc);
    if (lane == 0) atomicAdd(&cnts[cur], cnt);
}

// ---------------- final: out = (sums/cnt) @ lin_w + lin_b ----------------
__global__ __launch_bounds__(256) void final_kernel(
    const float* __restrict__ sums, const float* __restrict__ cnts,
    const float* __restrict__ lin_w, const float* __restrict__ lin_b,
    float* __restrict__ out, int total) {
    int tid = blockIdx.x * blockDim.x + threadIdx.x;
    if (tid >= total) return;
    int g = tid >> 5, o = tid & 31;
    float inv = 1.f / fmaxf(cnts[g], 1.f);
    float a = 0.f;
    for (int h = 0; h < 64; ++h) a += sums[g * 64 + h] * lin_w[h * 32 + o];
    out[tid] = a * inv + lin_b[o];
}

extern "C" void kernel_launch(void* const* d_in, const int* in_sizes, int n_in,
                              void* d_out, int out_size, void* d_ws, size_t ws_size,
                              hipStream_t stream) {
    const float* x     = (const float*)d_in[0];
    const int*   ei    = (const int*)d_in[1];
    const int*   batch = (const int*)d_in[2];
    const float* Wl1   = (const float*)d_in[3];
    const float* bl1   = (const float*)d_in[4];
    const float* Wr1   = (const float*)d_in[5];
    const float* br1   = (const float*)d_in[6];
    const float* att1  = (const float*)d_in[7];
    const float* bias1 = (const float*)d_in[8];
    const float* Wl2   = (const float*)d_in[9];
    const float* bl2   = (const float*)d_in[10];
    const float* Wr2   = (const float*)d_in[11];
    const float* br2   = (const float*)d_in[12];
    const float* att2  = (const float*)d_in[13];
    const float* bias2 = (const float*)d_in[14];
    const float* lin_w = (const float*)d_in[15];
    const float* lin_b = (const float*)d_in[16];
    float* out = (float*)d_out;

    const int N = in_sizes[0] / 64;
    const int E = in_sizes[1] / 2;
    const int G = out_size / 32;
    const int* src = ei;
    const int* dst = ei + E;

    // ---- workspace carve-up (256B-aligned) ----
    char*  ws  = (char*)d_ws;
    size_t off = 0;
    auto alloc = [&](size_t bytes) -> void* {
        void* p = ws + off;
        off += bytes;
        off = (off + 255) & ~(size_t)255;
        return p;
    };
    float* xl      = (float*)alloc((size_t)N * 64 * sizeof(float));
    float* xr      = (float*)alloc((size_t)N * 64 * sizeof(float));
    float* h1      = (float*)alloc((size_t)N * 64 * sizeof(float));  // also h2
    // zeroed region (contiguous): cnt, novf, sums, cnts
    int*   cnt     = (int*)alloc((size_t)N * sizeof(int));
    int*   novf    = (int*)alloc(256);
    float* sums    = (float*)alloc((size_t)G * 64 * sizeof(float));
    float* cnts    = (float*)alloc((size_t)G * sizeof(float));
    char*  zend    = ws + off;
    int*   ell     = (int*)alloc((size_t)N * ELLC * sizeof(int));
    int*   ovf_dst = (int*)alloc((size_t)OVF_CAP * sizeof(int));
    int*   ovf_src = (int*)alloc((size_t)OVF_CAP * sizeof(int));

    hipMemsetAsync(cnt, 0, (size_t)(zend - (char*)cnt), stream);

    int egrid = (E + 255) / 256;
    int ggrid = (N + GROWS - 1) / GROWS;
    int agrid = (N + 3) / 4;  // 4 waves/block, 1 wave per dst node

    // ---- ELL build (one pass) ----
    ell_fill_kernel<<<egrid, 256, 0, stream>>>(src, dst, cnt, ell,
                                               novf, ovf_dst, ovf_src, E);

    // ---- layer 1 ----
    dual_gemm64_kernel<<<ggrid, 256, 0, stream>>>(x, Wl1, bl1, Wr1, br1, xl, xr, N);
    gat_aggregate_kernel<<<agrid, 256, 0, stream>>>(
        xl, xr, cnt, ell, novf, ovf_dst, ovf_src, att1, bias1, h1, N);

    // ---- layer 2 (h2 aliases h1: gemm2 consumes h1, agg2 overwrites it) ----
    dual_gemm64_kernel<<<ggrid, 256, 0, stream>>>(h1, Wl2, bl2, Wr2, br2, xl, xr, N);
    gat_aggregate_kernel<<<agrid, 256, 0, stream>>>(
        xl, xr, cnt, ell, novf, ovf_dst, ovf_src, att2, bias2, h1, N);

    // ---- pool + final linear ----
    const int NWAVES = 1024;
    pool_kernel<<<256, 256, 0, stream>>>(h1, batch, sums, cnts, N, NWAVES);
    int total = G * 32;
    final_kernel<<<(total + 255) / 256, 256, 0, stream>>>(sums, cnts, lin_w, lin_b, out, total);
}